// Round 3
// baseline (18661.298 us; speedup 1.0000x reference)
//
#include <hip/hip_runtime.h>
#include <hip/hip_cooperative_groups.h>
#include <stdint.h>

namespace cg = cooperative_groups;

typedef __bf16 b8v __attribute__((ext_vector_type(8)));
typedef float  f4v __attribute__((ext_vector_type(4)));

#define NB      256
#define NSTAGE  260

__device__ __forceinline__ float sigm(float x) { return 1.0f / (1.0f + __expf(-x)); }
__device__ __forceinline__ float tanh_f(float x) {
  float ax = fabsf(x);
  float e = __expf(-2.0f * ax);
  float m = (1.0f - e) / (1.0f + e);
  return x >= 0.0f ? m : -m;
}
__device__ __forceinline__ b8v cvt8(f4v lo, f4v hi) {
  b8v v;
  v[0] = (__bf16)lo[0]; v[1] = (__bf16)lo[1]; v[2] = (__bf16)lo[2]; v[3] = (__bf16)lo[3];
  v[4] = (__bf16)hi[0]; v[5] = (__bf16)hi[1]; v[6] = (__bf16)hi[2]; v[7] = (__bf16)hi[3];
  return v;
}

// Persistent wavefront-pipelined GRU + fused projection. All I/O float32;
// bf16 MFMA internally (weights/x/h converted on the fly, fp32 accum).
// 256 blocks: l = bid>>6 in {0,1,2}=GRU layer, 3=output projection.
// Stage t: layer l computes step u = t - l. grid.sync() per stage.
// ws usage: hb32 = 3 layers * 2 parity * 64*1024 f32 = 1.5 MB only.
__global__ __launch_bounds__(256) void dec_main(
    const int* __restrict__ y,
    const float* __restrict__ embed,
    const float* __restrict__ Wih,
    const float* __restrict__ Whh,
    const float* __restrict__ bih,
    const float* __restrict__ bhh,
    const float* __restrict__ initS,
    const float* __restrict__ linW,
    const float* __restrict__ linb,
    float* __restrict__ out,
    unsigned char* __restrict__ ws)
{
  cg::grid_group grid = cg::this_grid();

  __shared__ b8v a_lds[2048];            // 32 KB, frag order [sec*16+k8][b]
  __shared__ float gate_lds[4][64][17];  // r,z,i_n,h_n preacts
  __shared__ int tok_lds[64];

  const int tid = threadIdx.x;
  const int bid = blockIdx.x;
  const int l   = bid >> 6;
  const int c0  = (bid & 63) << 4;
  const int wv  = tid >> 6;        // gate waves: 0:r 1:z 2:i_n 3:h_n
  const int lane = tid & 63;
  const int lq = lane >> 4;
  const int ln = lane & 15;

  float* hb32 = (float*)ws;        // [l*2+parity][b][1024] f32

  const int rowoff = (wv == 0) ? c0 : (wv == 1) ? (1024 + c0) : (2048 + c0);
  const size_t wl = (size_t)(l < 3 ? l : 0) * 3072 * 1024;
  const float* WihL = Wih + wl;
  const float* WhhL = Whh + wl;

  for (int t = 0; t < NSTAGE; ++t) {
    const int u = t - l;
    const bool active = (u >= 0) && (u <= 256);   // block-uniform
    const int rp = (t + 1) & 1;
    const int wp = t & 1;
    if (active) {
      if (l == 0 && tid < 64)
        tok_lds[tid] = (u == 0) ? 100 : y[(tid << 8) + (u - 1)];

      if (l < 3) {
        // ---------------- GRU layer ----------------
        f4v acc[4];
        #pragma unroll
        for (int mi = 0; mi < 4; ++mi) acc[mi] = (f4v){0.f, 0.f, 0.f, 0.f};

        const float* xbase = (l == 0) ? embed : (hb32 + (((l - 1) * 2 + rp) << 16));
        const float* hbase = hb32 + ((l * 2 + rp) << 16);

        for (int s = 0; s < 8; ++s) {            // K chunks of 128
          __syncthreads();
          #pragma unroll
          for (int i = 0; i < 8; ++i) {          // stage 2048 groups of 8 bf16
            int g   = tid + (i << 8);
            int sec = g >> 10;                   // 0=x 1=h
            int gg  = g & 1023;
            int b   = gg & 63;
            int k8  = gg >> 6;                   // 0..15
            int koff = (s << 7) + (k8 << 3);
            const float* src;
            if (sec == 0) {
              if (l == 0) src = embed + ((size_t)tok_lds[b] << 10) + koff;
              else        src = xbase + (b << 10) + koff;
            } else {
              if (u == 0) src = initS + (l << 10) + koff;  // broadcast init row
              else        src = hbase + (b << 10) + koff;
            }
            f4v lo = *(const f4v*)src;
            f4v hi = *(const f4v*)(src + 4);
            a_lds[((sec << 4) + k8) * 64 + b] = cvt8(lo, hi);
          }
          __syncthreads();
          const int pstart = (wv == 3) ? 1 : 0;
          const int pend   = (wv == 2) ? 1 : 2;
          for (int part = pstart; part < pend; ++part) {
            const float* wrow = ((part == 0) ? WihL : WhhL)
                              + (size_t)(rowoff + ln) * 1024 + (s << 7) + (lq << 3);
            #pragma unroll
            for (int tt = 0; tt < 4; ++tt) {
              f4v wlo = *(const f4v*)(wrow + (tt << 5));
              f4v whi = *(const f4v*)(wrow + (tt << 5) + 4);
              b8v bf = cvt8(wlo, whi);
              int fb = ((part << 4) + (tt << 2) + lq) * 64 + ln;
              #pragma unroll
              for (int mi = 0; mi < 4; ++mi) {
                acc[mi] = __builtin_amdgcn_mfma_f32_16x16x32_bf16(
                            a_lds[fb + (mi << 4)], bf, acc[mi], 0, 0, 0);
              }
            }
          }
        }
        #pragma unroll
        for (int mi = 0; mi < 4; ++mi)
          #pragma unroll
          for (int r = 0; r < 4; ++r)
            gate_lds[wv][(mi << 4) + (lq << 2) + r][ln] = acc[mi][r];
        __syncthreads();
        {
          const int b  = tid >> 2;
          const int cc = (tid & 3) << 2;
          const int cg = c0 + cc;
          const float* biL = bih + l * 3072;
          const float* bhL = bhh + l * 3072;
          float hold[4];
          if (u == 0) {
            #pragma unroll
            for (int j = 0; j < 4; ++j) hold[j] = initS[(l << 10) + cg + j];
          } else {
            const float* hp = hb32 + ((size_t)(l * 2 + rp) << 16) + (b << 10) + cg;
            #pragma unroll
            for (int j = 0; j < 4; ++j) hold[j] = hp[j];
          }
          float* o32 = hb32 + ((size_t)(l * 2 + wp) << 16) + (b << 10) + cg;
          #pragma unroll
          for (int j = 0; j < 4; ++j) {
            int c = cg + j;
            float rpre = gate_lds[0][b][cc + j] + biL[c]        + bhL[c];
            float zpre = gate_lds[1][b][cc + j] + biL[1024 + c] + bhL[1024 + c];
            float inn  = gate_lds[2][b][cc + j] + biL[2048 + c];
            float hnn  = gate_lds[3][b][cc + j] + bhL[2048 + c];
            float rg = sigm(rpre);
            float zg = sigm(zpre);
            float ng = tanh_f(inn + rg * hnn);
            o32[j] = (1.0f - zg) * ng + zg * hold[j];
          }
        }
      } else {
        // ---------------- output projection (pipeline layer 3) ----------------
        // out[b,u,:] = h2(u) @ lin_W^T + lin_b ; this block: cols c0..c0+15,
        // wave wv: batches wv*16..wv*16+15.
        f4v acc1 = (f4v){0.f, 0.f, 0.f, 0.f};
        const float* xbase = hb32 + ((4 + rp) << 16);   // layer-2 h buffer
        for (int s = 0; s < 8; ++s) {
          __syncthreads();
          #pragma unroll
          for (int i = 0; i < 4; ++i) {                 // stage 1024 groups
            int g = tid + (i << 8);
            int b = g & 63, k8 = g >> 6;                // k8 0..15
            const float* src = xbase + (b << 10) + (s << 7) + (k8 << 3);
            f4v lo = *(const f4v*)src;
            f4v hi = *(const f4v*)(src + 4);
            a_lds[k8 * 64 + b] = cvt8(lo, hi);
          }
          __syncthreads();
          const float* wrow = linW + (size_t)(c0 + ln) * 1024 + (s << 7) + (lq << 3);
          #pragma unroll
          for (int tt = 0; tt < 4; ++tt) {
            f4v wlo = *(const f4v*)(wrow + (tt << 5));
            f4v whi = *(const f4v*)(wrow + (tt << 5) + 4);
            b8v bf = cvt8(wlo, whi);
            acc1 = __builtin_amdgcn_mfma_f32_16x16x32_bf16(
                     a_lds[((tt << 2) + lq) * 64 + (wv << 4) + ln], bf, acc1, 0, 0, 0);
          }
        }
        const float bias = linb[c0 + ln];
        #pragma unroll
        for (int r = 0; r < 4; ++r) {
          int b = (wv << 4) + (lq << 2) + r;
          out[((size_t)(b * 257 + u) << 10) + c0 + ln] = acc1[r] + bias;
        }
      }
    }
    grid.sync();
  }
}

extern "C" void kernel_launch(void* const* d_in, const int* in_sizes, int n_in,
                              void* d_out, int out_size, void* d_ws, size_t ws_size,
                              hipStream_t stream) {
  const int* y        = (const int*)d_in[0];
  // d_in[1] = U (unused by the math, per reference)
  const float* embed  = (const float*)d_in[2];
  const float* Wih    = (const float*)d_in[3];
  const float* Whh    = (const float*)d_in[4];
  const float* bih    = (const float*)d_in[5];
  const float* bhh    = (const float*)d_in[6];
  const float* initS  = (const float*)d_in[7];
  const float* linW   = (const float*)d_in[8];
  const float* linb   = (const float*)d_in[9];
  float* out = (float*)d_out;
  unsigned char* ws = (unsigned char*)d_ws;

  void* args[] = {(void*)&y, (void*)&embed, (void*)&Wih, (void*)&Whh,
                  (void*)&bih, (void*)&bhh, (void*)&initS, (void*)&linW,
                  (void*)&linb, (void*)&out, (void*)&ws};
  hipLaunchCooperativeKernel((void*)dec_main, dim3(NB), dim3(256), args, 0, stream);
}

// Round 5
// 12597.674 us; speedup vs baseline: 1.4813x; 1.4813x over previous
//
#include <hip/hip_runtime.h>
#include <hip/hip_cooperative_groups.h>
#include <stdint.h>

namespace cg = cooperative_groups;

typedef unsigned short u16;
typedef __bf16 b8v __attribute__((ext_vector_type(8)));
typedef float  f4v __attribute__((ext_vector_type(4)));

#define NB      256
#define NSTAGE  260

// ws layout (fast path)
#define WS_HB16   0UL          // 3*2*64*1024 bf16 = 768 KB
#define WS_INIT16 786432UL     // 3*1024 bf16
#define WS_EMB16  792576UL     // 101*1024 bf16
#define WS_PWG    1048576UL    // GRU swizzled weights: 3*64 tiles * 6 q * 32 KB = 36 MB
#define WS_PWP    38797312UL   // proj swizzled: 64 tiles * 32 KB = 2 MB
#define WS_NEED   40894464UL

#define N_GRU_GRP  2359296     // 3*64*6*2048 16B-groups
#define N_PRJ_GRP  131072      // 64*2048
#define N_EMB_GRP  12928       // 101*1024/8
#define N_TOT_GRP  2503680

__device__ __forceinline__ float sigm(float x) { return 1.0f / (1.0f + __expf(-x)); }
__device__ __forceinline__ float tanh_f(float x) {
  float ax = fabsf(x);
  float e = __expf(-2.0f * ax);
  float m = (1.0f - e) / (1.0f + e);
  return x >= 0.0f ? m : -m;
}
__device__ __forceinline__ u16 f2b(float f) {
  union { float f; uint32_t u; } x; x.f = f;
  uint32_t r = x.u + 0x7fffu + ((x.u >> 16) & 1u);
  return (u16)(r >> 16);
}
__device__ __forceinline__ b8v cvt8(f4v lo, f4v hi) {
  b8v v;
  v[0] = (__bf16)lo[0]; v[1] = (__bf16)lo[1]; v[2] = (__bf16)lo[2]; v[3] = (__bf16)lo[3];
  v[4] = (__bf16)hi[0]; v[5] = (__bf16)hi[1]; v[6] = (__bf16)hi[2]; v[7] = (__bf16)hi[3];
  return v;
}
__device__ __forceinline__ void dma16(const u16* g, void* lds) {
  __builtin_amdgcn_global_load_lds(
      (const __attribute__((address_space(1))) unsigned int*)g,
      (__attribute__((address_space(3))) unsigned int*)lds, 16, 0, 0);
}

// ---------- prep: bf16-convert + swizzle weights into per-wave streams ----------
// GRU stream (l,ct,q): q = gate*2+p (gate 0=r,1=z,2=n; p 0=Wih,1=Whh).
// Stream layout: [s(8)][tt(4)][lane(64)] 16B groups; lane=(lq,ln):
//   element j: W[gate*1024 + ct*16 + ln][s*128 + tt*32 + lq*8 + j]
__global__ __launch_bounds__(256) void prep(
    const float* __restrict__ embed, const float* __restrict__ Wih,
    const float* __restrict__ Whh, const float* __restrict__ initS,
    const float* __restrict__ linW, unsigned char* __restrict__ ws)
{
  int idx = blockIdx.x * 256 + threadIdx.x;
  if (idx < N_GRU_GRP) {
    int sid = idx >> 11, w = idx & 2047;
    int q = sid % 6, lct = sid / 6;
    int ct = lct & 63, l = lct >> 6;
    int s = w >> 8, tt = (w >> 6) & 3, lane = w & 63;
    int gate = q >> 1, p = q & 1;
    int row = gate * 1024 + ct * 16 + (lane & 15);
    int k0  = s * 128 + tt * 32 + (lane >> 4) * 8;
    const float* src = (p ? Whh : Wih) + (size_t)l * 3145728 + (size_t)row * 1024 + k0;
    *(b8v*)(ws + WS_PWG + (size_t)idx * 16) =
        cvt8(*(const f4v*)src, *(const f4v*)(src + 4));
  } else if (idx < N_GRU_GRP + N_PRJ_GRP) {
    int i2 = idx - N_GRU_GRP;
    int ct = i2 >> 11, w = i2 & 2047;
    int s = w >> 8, tt = (w >> 6) & 3, lane = w & 63;
    int row = ct * 16 + (lane & 15);
    int k0  = s * 128 + tt * 32 + (lane >> 4) * 8;
    const float* src = linW + (size_t)row * 1024 + k0;
    *(b8v*)(ws + WS_PWP + (size_t)i2 * 16) =
        cvt8(*(const f4v*)src, *(const f4v*)(src + 4));
  } else if (idx < N_GRU_GRP + N_PRJ_GRP + N_EMB_GRP) {
    int i3 = idx - (N_GRU_GRP + N_PRJ_GRP);
    const float* src = embed + (size_t)i3 * 8;
    *(b8v*)(ws + WS_EMB16 + (size_t)i3 * 16) =
        cvt8(*(const f4v*)src, *(const f4v*)(src + 4));
  } else if (idx < N_TOT_GRP) {
    int i4 = idx - (N_GRU_GRP + N_PRJ_GRP + N_EMB_GRP);
    const float* src = initS + (size_t)i4 * 8;
    *(b8v*)(ws + WS_INIT16 + (size_t)i4 * 16) =
        cvt8(*(const f4v*)src, *(const f4v*)(src + 4));
  }
}

// ---------- fast main: persistent wavefront pipeline, bf16 streams + LDS DMA ----------
// LDS total = 32768 (a_lds) + 17408 (gate_lds) + 256 (tok) = 50432 B  (< 64 KB limit!)
__global__ __launch_bounds__(256) void dec_fast(
    const int* __restrict__ y,
    const float* __restrict__ bih, const float* __restrict__ bhh,
    const float* __restrict__ initS, const float* __restrict__ linb,
    float* __restrict__ out, unsigned char* __restrict__ ws)
{
  cg::grid_group grid = cg::this_grid();

  __shared__ b8v a_lds[2048];            // 32 KB: [sec(2)*16+k8(16)][b(64)] 16B
  __shared__ float gate_lds[4][64][17];
  __shared__ int tok_lds[64];

  const int tid = threadIdx.x;
  const int bid = blockIdx.x;
  const int l   = bid >> 6;
  const int ct  = bid & 63;
  const int c0  = ct << 4;
  const int wv  = tid >> 6;
  const int lane = tid & 63;
  const int lq = lane >> 4;
  const int ln = lane & 15;

  u16* hb16  = (u16*)(ws + WS_HB16);
  const u16* ini16 = (const u16*)(ws + WS_INIT16);
  const u16* emb16 = (const u16*)(ws + WS_EMB16);

  const unsigned char* wstream = (l < 3)
      ? ws + WS_PWG + ((size_t)(l * 64 + ct) * 196608)
      : ws + WS_PWP + ((size_t)ct * 32768);
  const int qbase = (wv < 2) ? wv * 2 : wv + 2;   // wv0:{0,1} wv1:{2,3} wv2:{4} wv3:{5}
  const int nq    = (wv < 2) ? 2 : 1;

  const int eb = tid >> 2;
  const int cc = (tid & 3) << 2;
  const int cg = c0 + cc;
  float hold[4];
  float rb[4], zb[4], ib[4], hbv[4];
  if (l < 3) {
    const float* biL = bih + l * 3072;
    const float* bhL = bhh + l * 3072;
    #pragma unroll
    for (int j = 0; j < 4; ++j) {
      hold[j] = initS[(l << 10) + cg + j];
      rb[j]  = biL[cg + j]        + bhL[cg + j];
      zb[j]  = biL[1024 + cg + j] + bhL[1024 + cg + j];
      ib[j]  = biL[2048 + cg + j];
      hbv[j] = bhL[2048 + cg + j];
    }
  }
  const float bias_p = (l == 3) ? linb[c0 + ln] : 0.0f;

  for (int t = 0; t < NSTAGE; ++t) {
    const int u = t - l;
    const bool active = (u >= 0) && (u <= 256);
    const int rp = (t + 1) & 1;
    const int wp = t & 1;
    if (active) {
      if (l == 0 && tid < 64)
        tok_lds[tid] = (u == 0) ? 100 : y[(tid << 8) + (u - 1)];

      if (l < 3) {
        // ---------------- GRU layer ----------------
        f4v acc[4];
        #pragma unroll
        for (int mi = 0; mi < 4; ++mi) acc[mi] = (f4v){0.f, 0.f, 0.f, 0.f};

        const u16* xb16 = hb16 + ((((l - 1) * 2 + rp) << 16));  // l>0 only
        const u16* hrow0 = (u == 0) ? (ini16 + (l << 10))
                                    : (hb16 + ((l * 2 + rp) << 16) + (lane << 10));

        for (int s = 0; s < 8; ++s) {     // K chunks of 128
          __syncthreads();
          const u16* xrow;
          if (l == 0) { int tokb = tok_lds[lane]; xrow = emb16 + ((size_t)tokb << 10); }
          else        { xrow = xb16 + (lane << 10); }
          #pragma unroll
          for (int i = 0; i < 8; ++i) {   // 32 groups: gg = wv + i*4
            int gg = wv + (i << 2);       // sec = gg>>4, k8 = gg&15
            int koff = (s << 7) + ((gg & 15) << 3);
            const u16* src = (gg < 16) ? (xrow + koff) : (hrow0 + koff);
            dma16(src, (unsigned char*)a_lds + (size_t)gg * 1024);
          }
          __syncthreads();
          for (int qi = 0; qi < nq; ++qi) {
            const int q = qbase + qi;
            const int sec = q & 1;
            const b8v* wp8 = (const b8v*)(wstream + (size_t)q * 32768 + (size_t)s * 4096);
            #pragma unroll
            for (int tt = 0; tt < 4; ++tt) {
              b8v bf = wp8[(tt << 6) + lane];
              int fb = ((sec << 4) + (tt << 2) + lq) << 6;
              #pragma unroll
              for (int mi = 0; mi < 4; ++mi)
                acc[mi] = __builtin_amdgcn_mfma_f32_16x16x32_bf16(
                            a_lds[fb + (mi << 4) + ln], bf, acc[mi], 0, 0, 0);
            }
          }
        }
        #pragma unroll
        for (int mi = 0; mi < 4; ++mi)
          #pragma unroll
          for (int r = 0; r < 4; ++r)
            gate_lds[wv][(mi << 4) + (lq << 2) + r][ln] = acc[mi][r];
        __syncthreads();
        {
          u16* o16 = hb16 + ((l * 2 + wp) << 16) + (eb << 10) + cg;
          u16 pk[4];
          #pragma unroll
          for (int j = 0; j < 4; ++j) {
            float rpre = gate_lds[0][eb][cc + j] + rb[j];
            float zpre = gate_lds[1][eb][cc + j] + zb[j];
            float inn  = gate_lds[2][eb][cc + j] + ib[j];
            float hnn  = gate_lds[3][eb][cc + j] + hbv[j];
            float rg = sigm(rpre);
            float zg = sigm(zpre);
            float ng = tanh_f(inn + rg * hnn);
            float hn = (1.0f - zg) * ng + zg * hold[j];
            hold[j] = hn;
            pk[j] = f2b(hn);
          }
          *(ushort4*)o16 = make_ushort4(pk[0], pk[1], pk[2], pk[3]);
        }
      } else {
        // ---------------- output projection ----------------
        f4v acc1 = (f4v){0.f, 0.f, 0.f, 0.f};
        const u16* xrow = hb16 + ((4 + rp) << 16) + (lane << 10);
        for (int s = 0; s < 8; ++s) {
          __syncthreads();
          #pragma unroll
          for (int i = 0; i < 4; ++i) {
            int gg = wv + (i << 2);                 // 0..15 = k8
            dma16(xrow + (s << 7) + (gg << 3),
                  (unsigned char*)a_lds + (size_t)gg * 1024);
          }
          __syncthreads();
          const b8v* wp8 = (const b8v*)(wstream + (size_t)s * 4096);
          #pragma unroll
          for (int tt = 0; tt < 4; ++tt) {
            b8v bf = wp8[(tt << 6) + lane];
            acc1 = __builtin_amdgcn_mfma_f32_16x16x32_bf16(
                     a_lds[(((tt << 2) + lq) << 6) + (wv << 4) + ln], bf, acc1, 0, 0, 0);
          }
        }
        #pragma unroll
        for (int r = 0; r < 4; ++r) {
          int b = (wv << 4) + (lq << 2) + r;
          out[((size_t)(b * 257 + u) << 10) + c0 + ln] = acc1[r] + bias_p;
        }
      }
    }
    grid.sync();
  }
}

// ---------------- slow fallback (round-3 passing kernel) ----------------
__global__ __launch_bounds__(256) void dec_slow(
    const int* __restrict__ y, const float* __restrict__ embed,
    const float* __restrict__ Wih, const float* __restrict__ Whh,
    const float* __restrict__ bih, const float* __restrict__ bhh,
    const float* __restrict__ initS, const float* __restrict__ linW,
    const float* __restrict__ linb, float* __restrict__ out,
    unsigned char* __restrict__ ws)
{
  cg::grid_group grid = cg::this_grid();
  __shared__ b8v a_lds[2048];
  __shared__ float gate_lds[4][64][17];
  __shared__ int tok_lds[64];
  const int tid = threadIdx.x, bid = blockIdx.x;
  const int l = bid >> 6, c0 = (bid & 63) << 4;
  const int wv = tid >> 6, lane = tid & 63, lq = lane >> 4, ln = lane & 15;
  float* hb32 = (float*)ws;
  const int rowoff = (wv == 0) ? c0 : (wv == 1) ? (1024 + c0) : (2048 + c0);
  const size_t wl = (size_t)(l < 3 ? l : 0) * 3072 * 1024;
  const float* WihL = Wih + wl;
  const float* WhhL = Whh + wl;
  for (int t = 0; t < NSTAGE; ++t) {
    const int u = t - l;
    const bool active = (u >= 0) && (u <= 256);
    const int rp = (t + 1) & 1, wp = t & 1;
    if (active) {
      if (l == 0 && tid < 64)
        tok_lds[tid] = (u == 0) ? 100 : y[(tid << 8) + (u - 1)];
      if (l < 3) {
        f4v acc[4];
        #pragma unroll
        for (int mi = 0; mi < 4; ++mi) acc[mi] = (f4v){0.f, 0.f, 0.f, 0.f};
        const float* xbase = (l == 0) ? embed : (hb32 + (((l - 1) * 2 + rp) << 16));
        const float* hbase = hb32 + ((l * 2 + rp) << 16);
        for (int s = 0; s < 8; ++s) {
          __syncthreads();
          #pragma unroll
          for (int i = 0; i < 8; ++i) {
            int g = tid + (i << 8);
            int sec = g >> 10, gg = g & 1023, b = gg & 63, k8 = gg >> 6;
            int koff = (s << 7) + (k8 << 3);
            const float* src;
            if (sec == 0) src = (l == 0) ? embed + ((size_t)tok_lds[b] << 10) + koff
                                         : xbase + (b << 10) + koff;
            else src = (u == 0) ? initS + (l << 10) + koff : hbase + (b << 10) + koff;
            a_lds[((sec << 4) + k8) * 64 + b] = cvt8(*(const f4v*)src, *(const f4v*)(src + 4));
          }
          __syncthreads();
          const int pstart = (wv == 3) ? 1 : 0;
          const int pend = (wv == 2) ? 1 : 2;
          for (int part = pstart; part < pend; ++part) {
            const float* wrow = ((part == 0) ? WihL : WhhL)
                              + (size_t)(rowoff + ln) * 1024 + (s << 7) + (lq << 3);
            #pragma unroll
            for (int tt = 0; tt < 4; ++tt) {
              b8v bf = cvt8(*(const f4v*)(wrow + (tt << 5)), *(const f4v*)(wrow + (tt << 5) + 4));
              int fb = ((part << 4) + (tt << 2) + lq) * 64 + ln;
              #pragma unroll
              for (int mi = 0; mi < 4; ++mi)
                acc[mi] = __builtin_amdgcn_mfma_f32_16x16x32_bf16(a_lds[fb + (mi << 4)], bf, acc[mi], 0, 0, 0);
            }
          }
        }
        #pragma unroll
        for (int mi = 0; mi < 4; ++mi)
          #pragma unroll
          for (int r = 0; r < 4; ++r)
            gate_lds[wv][(mi << 4) + (lq << 2) + r][ln] = acc[mi][r];
        __syncthreads();
        {
          const int b = tid >> 2, cc = (tid & 3) << 2, cg = c0 + cc;
          const float* biL = bih + l * 3072;
          const float* bhL = bhh + l * 3072;
          float hold[4];
          if (u == 0) {
            #pragma unroll
            for (int j = 0; j < 4; ++j) hold[j] = initS[(l << 10) + cg + j];
          } else {
            const float* hp = hb32 + ((size_t)(l * 2 + rp) << 16) + (b << 10) + cg;
            #pragma unroll
            for (int j = 0; j < 4; ++j) hold[j] = hp[j];
          }
          float* o32 = hb32 + ((size_t)(l * 2 + wp) << 16) + (b << 10) + cg;
          #pragma unroll
          for (int j = 0; j < 4; ++j) {
            int c = cg + j;
            float rpre = gate_lds[0][b][cc + j] + biL[c] + bhL[c];
            float zpre = gate_lds[1][b][cc + j] + biL[1024 + c] + bhL[1024 + c];
            float inn = gate_lds[2][b][cc + j] + biL[2048 + c];
            float hnn = gate_lds[3][b][cc + j] + bhL[2048 + c];
            float rg = sigm(rpre), zg = sigm(zpre);
            float ng = tanh_f(inn + rg * hnn);
            o32[j] = (1.0f - zg) * ng + zg * hold[j];
          }
        }
      } else {
        f4v acc1 = (f4v){0.f, 0.f, 0.f, 0.f};
        const float* xbase = hb32 + ((4 + rp) << 16);
        for (int s = 0; s < 8; ++s) {
          __syncthreads();
          #pragma unroll
          for (int i = 0; i < 4; ++i) {
            int g = tid + (i << 8);
            int b = g & 63, k8 = g >> 6;
            const float* src = xbase + (b << 10) + (s << 7) + (k8 << 3);
            a_lds[k8 * 64 + b] = cvt8(*(const f4v*)src, *(const f4v*)(src + 4));
          }
          __syncthreads();
          const float* wrow = linW + (size_t)(c0 + ln) * 1024 + (s << 7) + (lq << 3);
          #pragma unroll
          for (int tt = 0; tt < 4; ++tt) {
            b8v bf = cvt8(*(const f4v*)(wrow + (tt << 5)), *(const f4v*)(wrow + (tt << 5) + 4));
            acc1 = __builtin_amdgcn_mfma_f32_16x16x32_bf16(
                     a_lds[((tt << 2) + lq) * 64 + (wv << 4) + ln], bf, acc1, 0, 0, 0);
          }
        }
        const float bias = linb[c0 + ln];
        #pragma unroll
        for (int r = 0; r < 4; ++r) {
          int b = (wv << 4) + (lq << 2) + r;
          out[((size_t)(b * 257 + u) << 10) + c0 + ln] = acc1[r] + bias;
        }
      }
    }
    grid.sync();
  }
}

extern "C" void kernel_launch(void* const* d_in, const int* in_sizes, int n_in,
                              void* d_out, int out_size, void* d_ws, size_t ws_size,
                              hipStream_t stream) {
  const int* y        = (const int*)d_in[0];
  const float* embed  = (const float*)d_in[2];
  const float* Wih    = (const float*)d_in[3];
  const float* Whh    = (const float*)d_in[4];
  const float* bih    = (const float*)d_in[5];
  const float* bhh    = (const float*)d_in[6];
  const float* initS  = (const float*)d_in[7];
  const float* linW   = (const float*)d_in[8];
  const float* linb   = (const float*)d_in[9];
  float* out = (float*)d_out;
  unsigned char* ws = (unsigned char*)d_ws;

  bool fast_ok = false;
  if (ws_size >= WS_NEED) {
    hipLaunchKernelGGL(prep, dim3(N_TOT_GRP / 256), dim3(256), 0, stream,
                       embed, Wih, Whh, initS, linW, ws);
    void* args[] = {(void*)&y, (void*)&bih, (void*)&bhh, (void*)&initS,
                    (void*)&linb, (void*)&out, (void*)&ws};
    fast_ok = (hipLaunchCooperativeKernel((void*)dec_fast, dim3(NB), dim3(256),
                                          args, 0, stream) == hipSuccess);
  }
  if (!fast_ok) {
    void* args[] = {(void*)&y, (void*)&embed, (void*)&Wih, (void*)&Whh,
                    (void*)&bih, (void*)&bhh, (void*)&initS, (void*)&linW,
                    (void*)&linb, (void*)&out, (void*)&ws};
    hipLaunchCooperativeKernel((void*)dec_slow, dim3(NB), dim3(256), args, 0, stream);
  }
}